// Round 6
// baseline (131.782 us; speedup 1.0000x reference)
//
#include <hip/hip_runtime.h>
#include <math.h>

#ifndef __has_builtin
#define __has_builtin(x) 0
#endif
#if __has_builtin(__builtin_amdgcn_exp2f)
#define EXP2F(x) __builtin_amdgcn_exp2f(x)
#else
#define EXP2F(x) exp2f(x)
#endif
#if __has_builtin(__builtin_amdgcn_rcpf)
#define RCPF(x) __builtin_amdgcn_rcpf(x)
#else
#define RCPF(x) (1.0f / (x))
#endif

typedef _Float16 f16x8 __attribute__((ext_vector_type(8)));
typedef _Float16 h2 __attribute__((ext_vector_type(2)));
typedef float f32x4 __attribute__((ext_vector_type(4)));

union Frag {
  f16x8 v;
  h2 p[4];
};

__device__ __forceinline__ h2 pkrtz(float a, float b) {
#if __has_builtin(__builtin_amdgcn_cvt_pkrtz)
  return __builtin_bit_cast(h2, __builtin_amdgcn_cvt_pkrtz(a, b));
#else
  h2 r; r.x = (_Float16)a; r.y = (_Float16)b; return r;
#endif
}

// RTZ-truncate an fp32 (known positive, < 65504, not NaN) to the nearest
// fp16-representable value BELOW it, staying in fp32. Equals (float)pkrtz(w)
// for normal-range w; for w < 2^-14 the residual path still bounds error
// by ~2^-24 absolute (negligible mass).
__device__ __forceinline__ float trunc16(float w) {
  return __builtin_bit_cast(float, __builtin_bit_cast(unsigned int, w) & 0xFFFFE000u);
}

constexpr int KBINS = 32;
constexpr int MM_BLOCKS = 512;     // minmax stage-1 blocks
constexpr int MAIN_BLOCKS = 1024;  // main kernel blocks
constexpr int NTHR = 512;          // 8 waves/block -> up to 32 waves/CU
constexpr int WPB = 8;
constexpr int BATCH = 32;          // samples per wave-batch == MFMA K
constexpr int NSLOT = 64;          // atomic accumulator slots (16 contenders each)
constexpr int ACC_OFF_F = 4096;    // float offset of fp64 accumulator (byte 16384)
// scale: A' = e_a * 4096 / (sa*sb), B' = 64 * e_b  ->  A'*B' = w_a*w_b * 2^18

#define MFMA16(a, b, c) __builtin_amdgcn_mfma_f32_16x16x32_f16((a), (b), (c), 0, 0, 0)

// 16-lane DPP row sum via rotate-accumulate (pure VALU, no DS pipe)
template <int CTRL>
__device__ __forceinline__ float rot_add(float v) {
  int r = __builtin_amdgcn_update_dpp(0, __builtin_bit_cast(int, v), CTRL, 0xF, 0xF, true);
  return v + __builtin_bit_cast(float, r);
}
__device__ __forceinline__ float row_sum16(float v) {
  v = rot_add<0x128>(v);  // row_ror:8
  v = rot_add<0x124>(v);  // row_ror:4
  v = rot_add<0x122>(v);  // row_ror:2
  v = rot_add<0x121>(v);  // row_ror:1
  return v;
}

// raw (unnormalized) Parzen exps for bins m (e0) and m+16 (e1) + 32-bin row sum
__device__ __forceinline__ void eraw(float x, float c0, float c1, float npl2,
                                     float& e0, float& e1, float& s) {
  float d0 = x - c0, d1 = x - c1;
  e0 = EXP2F((npl2 * d0) * d0);
  e1 = EXP2F((npl2 * d1) * d1);
  s = row_sum16(e0 + e1);
}

// ---------------- Stage 0: global min/max + accumulator zeroing ----------------
__global__ __launch_bounds__(256) void k_minmax(const float* __restrict__ p,
                                                const float* __restrict__ t,
                                                int n, float* __restrict__ ws) {
  int tid = blockIdx.x * 256 + threadIdx.x;
  int nth = gridDim.x * 256;
  // zero the fp64 atomic accumulator (poisoned 0xAA before every launch)
  if (tid < NSLOT * 1024) ((double*)(ws + ACC_OFF_F))[tid] = 0.0;

  float mn = INFINITY, mx = -INFINITY;
  int n4 = n >> 2;
  const float4* p4 = (const float4*)p;
  const float4* t4 = (const float4*)t;
  for (int i = tid; i < n4; i += nth) {
    float4 a = p4[i];
    mn = fminf(mn, fminf(fminf(a.x, a.y), fminf(a.z, a.w)));
    mx = fmaxf(mx, fmaxf(fmaxf(a.x, a.y), fmaxf(a.z, a.w)));
    float4 b = t4[i];
    mn = fminf(mn, fminf(fminf(b.x, b.y), fminf(b.z, b.w)));
    mx = fmaxf(mx, fmaxf(fmaxf(b.x, b.y), fmaxf(b.z, b.w)));
  }
  for (int i = (n4 << 2) + tid; i < n; i += nth) {
    mn = fminf(mn, fminf(p[i], t[i]));
    mx = fmaxf(mx, fmaxf(p[i], t[i]));
  }
  for (int off = 32; off; off >>= 1) {
    mn = fminf(mn, __shfl_xor(mn, off, 64));
    mx = fmaxf(mx, __shfl_xor(mx, off, 64));
  }
  __shared__ float smn[4], smx[4];
  int wv = threadIdx.x >> 6;
  if ((threadIdx.x & 63) == 0) { smn[wv] = mn; smx[wv] = mx; }
  __syncthreads();
  if (threadIdx.x == 0) {
    mn = fminf(fminf(smn[0], smn[1]), fminf(smn[2], smn[3]));
    mx = fmaxf(fmaxf(smx[0], smx[1]), fmaxf(smx[2], smx[3]));
    ws[16 + 2 * blockIdx.x] = mn;
    ws[17 + 2 * blockIdx.x] = mx;
  }
}

// -------- Stage 1: fragment-direct Parzen weights + MFMA joint histogram --------
// Lane (m=lane&15, quad=lane>>4): bins {m, m+16} x samples {quad*8+j} == the
// mfma_f32_16x16x32_f16 A/B fragment elements. fp16 hi/lo split via exponent-
// preserving mantissa mask (RTZ hi, exact fp32 residual, RTN lo) -- arithmetic
// identical to round-5, but every fragment write is a whole-register pack.
__global__ __launch_bounds__(NTHR, 4) void k_main(const float* __restrict__ p,
                                                  const float* __restrict__ t,
                                                  int n, float* __restrict__ ws) {
  __shared__ __align__(16) float red[WPB][KBINS * KBINS];  // 32 KB
  __shared__ float s_par[4];

  const int tidx = threadIdx.x;
  const int lane = tidx & 63;
  const int wv = tidx >> 6;

  // params from minmax partials (wave 0)
  if (tidx < 64) {
    float mn = INFINITY, mx = -INFINITY;
    for (int b = lane; b < MM_BLOCKS; b += 64) {
      mn = fminf(mn, ws[16 + 2 * b]);
      mx = fmaxf(mx, ws[17 + 2 * b]);
    }
    for (int off = 32; off; off >>= 1) {
      mn = fminf(mn, __shfl_xor(mn, off, 64));
      mx = fmaxf(mx, __shfl_xor(mx, off, 64));
    }
    if (lane == 0) {
      bool in_range = (mx <= 1.0f) && (mn >= 0.0f);
      float minv = in_range ? 0.0f : mn;
      float maxv = in_range ? 1.0f : mx;
      float drange = maxv - minv;
      float sigma = drange * (1.0f / (KBINS - 1));  // SIGMA_RATIO = 1
      float preterm = 1.0f / (2.0f * sigma * sigma);
      s_par[0] = minv;
      s_par[1] = drange * (1.0f / (KBINS - 1));     // bin spacing
      s_par[2] = preterm * 1.44269504088896340736f; // preterm * log2(e)
    }
  }
  __syncthreads();
  const float minv = s_par[0], delta = s_par[1];
  const float npl2 = -s_par[2];

  const int m = lane & 15;
  const int quad = lane >> 4;
  const int qb = quad << 3;
  const float c0 = fmaf(delta, (float)m, minv);
  const float c1 = fmaf(delta, (float)(m + 16), minv);

  f32x4 acc00 = {0.f, 0.f, 0.f, 0.f};
  f32x4 acc01 = {0.f, 0.f, 0.f, 0.f};
  f32x4 acc10 = {0.f, 0.f, 0.f, 0.f};
  f32x4 acc11 = {0.f, 0.f, 0.f, 0.f};

  const int per_wave = n >> 13;  // n / 8192 waves = 256
  const int base = (blockIdx.x * WPB + wv) * per_wave;

  // initial batch loads (quad-uniform 16B -> L1 broadcast, VMEM only)
  float4 a0 = *(const float4*)(p + base + qb);
  float4 a1 = *(const float4*)(p + base + qb + 4);
  float4 b0 = *(const float4*)(t + base + qb);
  float4 b1 = *(const float4*)(t + base + qb + 4);

  for (int it = 0; it < per_wave; it += BATCH) {
    float xa[8] = {a0.x, a0.y, a0.z, a0.w, a1.x, a1.y, a1.z, a1.w};
    float xb[8] = {b0.x, b0.y, b0.z, b0.w, b1.x, b1.y, b1.z, b1.w};
    // prefetch next batch while this one computes
    if (it + BATCH < per_wave) {
      const int nbase = base + it + BATCH + qb;
      a0 = *(const float4*)(p + nbase);
      a1 = *(const float4*)(p + nbase + 4);
      b0 = *(const float4*)(t + nbase);
      b1 = *(const float4*)(t + nbase + 4);
    }

    Frag Ah0, Al0, Ah1, Al1, Bh0, Bl0, Bh1, Bl1;
#pragma unroll
    for (int jp = 0; jp < 4; ++jp) {
      // raw exps + row sums for 2 A samples and 2 B samples
      float ea00, ea01, sa0, ea10, ea11, sa1;
      float eb00, eb01, sb0, eb10, eb11, sb1;
      eraw(xa[2 * jp],     c0, c1, npl2, ea00, ea01, sa0);
      eraw(xa[2 * jp + 1], c0, c1, npl2, ea10, ea11, sa1);
      eraw(xb[2 * jp],     c0, c1, npl2, eb00, eb01, sb0);
      eraw(xb[2 * jp + 1], c0, c1, npl2, eb10, eb11, sb1);
      // one rcp per sample pair: A' = e_a * 4096/(sa*sb), B' = 64*e_b
      float pr0 = sa0 * sb0;
      float i0 = RCPF(pr0);
      i0 = i0 * fmaf(-pr0, i0, 2.0f);  // Newton -> ~0.5 ulp
      i0 *= 4096.0f;
      float pr1 = sa1 * sb1;
      float i1 = RCPF(pr1);
      i1 = i1 * fmaf(-pr1, i1, 2.0f);
      i1 *= 4096.0f;
      float wa00 = ea00 * i0, wa01 = ea01 * i0;   // sample 0, bins m / m+16
      float wa10 = ea10 * i1, wa11 = ea11 * i1;   // sample 1
      float wb00 = eb00 * 64.0f, wb01 = eb01 * 64.0f;
      float wb10 = eb10 * 64.0f, wb11 = eb11 * 64.0f;
      // mask-split: hi = RTZ-truncated fp32 (exact pkrtz), lo = exact residual
      float H;
      H = trunc16(wa00); float la00 = wa00 - H; float ha00 = H;
      H = trunc16(wa10); float la10 = wa10 - H; float ha10 = H;
      H = trunc16(wa01); float la01 = wa01 - H; float ha01 = H;
      H = trunc16(wa11); float la11 = wa11 - H; float ha11 = H;
      H = trunc16(wb00); float lb00 = wb00 - H; float hb00 = H;
      H = trunc16(wb10); float lb10 = wb10 - H; float hb10 = H;
      H = trunc16(wb01); float lb01 = wb01 - H; float hb01 = H;
      H = trunc16(wb11); float lb11 = wb11 - H; float hb11 = H;
      // whole-register packs: hi exact via pkrtz, lo RTN via scalar cvt pair
      Ah0.p[jp] = pkrtz(ha00, ha10);
      Ah1.p[jp] = pkrtz(ha01, ha11);
      Bh0.p[jp] = pkrtz(hb00, hb10);
      Bh1.p[jp] = pkrtz(hb01, hb11);
      Al0.p[jp] = h2{(_Float16)la00, (_Float16)la10};
      Al1.p[jp] = h2{(_Float16)la01, (_Float16)la11};
      Bl0.p[jp] = h2{(_Float16)lb00, (_Float16)lb10};
      Bl1.p[jp] = h2{(_Float16)lb01, (_Float16)lb11};
    }
    // 4 tiles x 4 split terms (hh, lh, hl, ll)
    acc00 = MFMA16(Ah0.v, Bh0.v, acc00);
    acc01 = MFMA16(Ah0.v, Bh1.v, acc01);
    acc10 = MFMA16(Ah1.v, Bh0.v, acc10);
    acc11 = MFMA16(Ah1.v, Bh1.v, acc11);
    acc00 = MFMA16(Al0.v, Bh0.v, acc00);
    acc01 = MFMA16(Al0.v, Bh1.v, acc01);
    acc10 = MFMA16(Al1.v, Bh0.v, acc10);
    acc11 = MFMA16(Al1.v, Bh1.v, acc11);
    acc00 = MFMA16(Ah0.v, Bl0.v, acc00);
    acc01 = MFMA16(Ah0.v, Bl1.v, acc01);
    acc10 = MFMA16(Ah1.v, Bl0.v, acc10);
    acc11 = MFMA16(Ah1.v, Bl1.v, acc11);
    acc00 = MFMA16(Al0.v, Bl0.v, acc00);
    acc01 = MFMA16(Al0.v, Bl1.v, acc01);
    acc10 = MFMA16(Al1.v, Bl0.v, acc10);
    acc11 = MFMA16(Al1.v, Bl1.v, acc11);
  }

  // per-block reduction of 8 wave accumulators; C/D layout col=lane&15, row=quad*4+reg
#pragma unroll
  for (int reg = 0; reg < 4; ++reg) {
    int r0 = quad * 4 + reg;
    red[wv][r0 * KBINS + m] = acc00[reg];
    red[wv][r0 * KBINS + 16 + m] = acc01[reg];
    red[wv][(16 + r0) * KBINS + m] = acc10[reg];
    red[wv][(16 + r0) * KBINS + 16 + m] = acc11[reg];
  }
  __syncthreads();
  {
    int c = 2 * tidx;
    float s0 = 0.f, s1 = 0.f;
#pragma unroll
    for (int w = 0; w < WPB; ++w) {
      float2 v = *(const float2*)&red[w][c];
      s0 += v.x;
      s1 += v.y;
    }
    // fp64 atomics into slot (blockIdx & 63): 16 contenders/address
    double* acc = (double*)(ws + ACC_OFF_F) + (size_t)(blockIdx.x & (NSLOT - 1)) * 1024;
    unsafeAtomicAdd(&acc[c], (double)s0);
    unsafeAtomicAdd(&acc[c + 1], (double)s1);
  }
}

// ---------------- Stage 2: final fp64 reduce + MI formula ----------------
__global__ __launch_bounds__(1024) void k_final(const float* __restrict__ ws_f,
                                                float* __restrict__ out, int n) {
  const double* acc = (const double*)(ws_f + ACC_OFF_F);
  __shared__ double pab_s[1024];
  __shared__ double pa_s[32], pb_s[32];
  __shared__ double wsum[16];
  int tid = threadIdx.x;
  double s0 = 0.0, s1 = 0.0, s2 = 0.0, s3 = 0.0;
#pragma unroll
  for (int slot = 0; slot < NSLOT; slot += 4) {
    s0 += acc[(size_t)(slot + 0) * 1024 + tid];
    s1 += acc[(size_t)(slot + 1) * 1024 + tid];
    s2 += acc[(size_t)(slot + 2) * 1024 + tid];
    s3 += acc[(size_t)(slot + 3) * 1024 + tid];
  }
  double s = (s0 + s1) + (s2 + s3);
  // descale: A'*B' carried 2^18
  double pab = s / ((double)n * 262144.0);
  pab_s[tid] = pab;
  __syncthreads();
  if (tid < 32) {
    double a = 0.0;
    for (int l = 0; l < 32; ++l) a += pab_s[tid * 32 + l];
    pa_s[tid] = a;
  } else if (tid < 64) {
    int l = tid - 32;
    double b = 0.0;
    for (int k2 = 0; k2 < 32; ++k2) b += pab_s[k2 * 32 + l];
    pb_s[l] = b;
  }
  __syncthreads();
  int k = tid >> 5, l = tid & 31;
  double papb = pa_s[k] * pb_s[l];
  double v = pab * log((pab + 1e-7) / (papb + 1e-7) + 1e-7);
  for (int off = 32; off; off >>= 1) v += __shfl_down(v, off, 64);
  if ((tid & 63) == 0) wsum[tid >> 6] = v;
  __syncthreads();
  if (tid < 64) {
    double w = (tid < 16) ? wsum[tid] : 0.0;
    for (int off = 8; off; off >>= 1) w += __shfl_down(w, off, 64);
    if (tid == 0) out[0] = (float)(-w);
  }
}

extern "C" void kernel_launch(void* const* d_in, const int* in_sizes, int n_in,
                              void* d_out, int out_size, void* d_ws, size_t ws_size,
                              hipStream_t stream) {
  const float* p = (const float*)d_in[0];
  const float* t = (const float*)d_in[1];
  float* out = (float*)d_out;
  float* ws = (float*)d_ws;
  int n = in_sizes[0];  // 2,097,152

  k_minmax<<<dim3(MM_BLOCKS), dim3(256), 0, stream>>>(p, t, n, ws);
  k_main<<<dim3(MAIN_BLOCKS), dim3(NTHR), 0, stream>>>(p, t, n, ws);
  k_final<<<dim3(1), dim3(1024), 0, stream>>>(ws, out, n);
}